// Round 5
// baseline (611.109 us; speedup 1.0000x reference)
//
#include <hip/hip_runtime.h>
#include <math.h>

// ---- problem constants ----
static constexpr int kN     = 40000;
static constexpr int kE     = 1000000;
static constexpr int kFIN   = 128;
static constexpr int kHID   = 128;
static constexpr int kTDIM  = 16;
static constexpr int kG     = 64;
static constexpr int kDIN0  = kHID + kTDIM;   // 144
static constexpr int kPOOLC = 16;             // pooling chunks per group
#define LN_EPS 1e-5f
#define NEG_SLOPE 0.2f

__device__ __forceinline__ float leaky(float v) {
  return v > 0.f ? v : NEG_SLOPE * v;
}

// ---------- weight transpose: wt[k*J + j] = w[j*K + k] (classifier only) ----------
__global__ void k_transpose(const float* __restrict__ w, float* __restrict__ wt,
                            int J, int K) {
  int idx = blockIdx.x * 256 + threadIdx.x;
  if (idx >= J * K) return;
  int j = idx / K, k = idx - j * K;
  wt[k * J + j] = w[idx];
}

// ---------- CSR build ----------
__global__ void __launch_bounds__(256) k_hist(const int* __restrict__ dst, int* __restrict__ deg) {
  int e = blockIdx.x * 256 + threadIdx.x;
  if (e >= kE) return;
  atomicAdd(deg + dst[e], 1);
}

__global__ void __launch_bounds__(1024) k_scan(const int* __restrict__ deg,
                                               int* __restrict__ rowptr,
                                               int* __restrict__ cursor) {
  __shared__ int tmp[1024];
  int tid = threadIdx.x;
  int base = tid * 40;
  int s = 0;
  for (int i = 0; i < 40; ++i) {
    int idx = base + i;
    s += (idx < kN) ? deg[idx] : 0;
  }
  tmp[tid] = s;
  __syncthreads();
  for (int off = 1; off < 1024; off <<= 1) {
    int t = (tid >= off) ? tmp[tid - off] : 0;
    __syncthreads();
    tmp[tid] += t;
    __syncthreads();
  }
  int run = tmp[tid] - s;  // exclusive prefix of this thread's chunk
  for (int i = 0; i < 40; ++i) {
    int idx = base + i;
    if (idx < kN) { rowptr[idx] = run; cursor[idx] = run; run += deg[idx]; }
  }
  if (tid == 1023) rowptr[kN] = run;
}

__global__ void __launch_bounds__(256) k_scatter(
    const int* __restrict__ src, const int* __restrict__ dst,
    const float* __restrict__ ts, int* __restrict__ cursor,
    int* __restrict__ csr_src, float* __restrict__ csr_ts) {
  int e = blockIdx.x * 256 + threadIdx.x;
  if (e >= kE) return;
  int d = dst[e];
  int pos = atomicAdd(cursor + d, 1);
  csr_src[pos] = src[e];
  csr_ts[pos] = ts[e];
}

// ---------- time encoding gather: h[n,128+j] = sum_{e in(n)} cos(t_e*w[j]+b[j]) ----------
__global__ void __launch_bounds__(256) k_time_gather(
    const int* __restrict__ rowptr, const float* __restrict__ csr_ts,
    const float* __restrict__ tw, const float* __restrict__ tb,
    float* __restrict__ h) {
  int n = blockIdx.x * 4 + (threadIdx.x >> 6);
  if (n >= kN) return;
  int lane = threadIdx.x & 63;
  int j = lane & 15, grp = lane >> 4;
  float w = tw[j], b = tb[j];
  int lo = rowptr[n], hi = rowptr[n + 1];
  float s = 0.f;
  for (int p = lo + grp; p < hi; p += 4) {
    s += cosf(csr_ts[p] * w + b);
  }
  s += __shfl_xor(s, 16);
  s += __shfl_xor(s, 32);
  if (grp == 0) h[(size_t)n * kDIN0 + kHID + j] = s;
}

// ---------- GEMM: out[n,j] = bias[j] + sum_k in[n,k]*w[j,k]  (J=128) ----------
// 16 nodes/block, 8 acc/thread, float4 over k. w is ORIGINAL row-major [128][K].
__global__ void __launch_bounds__(256) k_gemm_f32(
    const float* __restrict__ in, int in_stride, int K,
    const float* __restrict__ w, const float* __restrict__ bias,
    float* __restrict__ out, int out_stride) {
  __shared__ float xs[16 * kDIN0];
  int n0 = blockIdx.x * 16;
  int tid = threadIdx.x;
  int total = 16 * K;
  for (int idx = tid * 4; idx < total; idx += 1024) {
    int nl = idx / K, k = idx - nl * K;
    *(float4*)(xs + idx) = *(const float4*)(in + (size_t)(n0 + nl) * in_stride + k);
  }
  __syncthreads();
  int j = tid & 127, g = tid >> 7;
  const float* wr = w + (size_t)j * K;
  const float* xr = xs + g * (8 * K);
  float acc[8] = {0.f, 0.f, 0.f, 0.f, 0.f, 0.f, 0.f, 0.f};
  for (int k = 0; k < K; k += 4) {
    float4 w4 = *(const float4*)(wr + k);
#pragma unroll
    for (int m = 0; m < 8; ++m) {
      float4 x4 = *(const float4*)(xr + m * K + k);
      acc[m] += w4.x * x4.x + w4.y * x4.y + w4.z * x4.z + w4.w * x4.w;
    }
  }
  float b = bias ? bias[j] : 0.f;
#pragma unroll
  for (int m = 0; m < 8; ++m)
    out[(size_t)(n0 + g * 8 + m) * out_stride + j] = acc[m] + b;
}

// ---------- xh = h @ W.T fused with att dot products (same structure) ----------
__global__ void __launch_bounds__(256) k_xh_att_f32(
    const float* __restrict__ in, int in_stride, int K,
    const float* __restrict__ w,
    const float* __restrict__ att_s, const float* __restrict__ att_d,
    float* __restrict__ xh, float* __restrict__ a_src, float* __restrict__ a_dst) {
  __shared__ float xs[16 * kDIN0];
  int n0 = blockIdx.x * 16;
  int tid = threadIdx.x;
  int total = 16 * K;
  for (int idx = tid * 4; idx < total; idx += 1024) {
    int nl = idx / K, k = idx - nl * K;
    *(float4*)(xs + idx) = *(const float4*)(in + (size_t)(n0 + nl) * in_stride + k);
  }
  __syncthreads();
  int j = tid & 127, g = tid >> 7;
  const float* wr = w + (size_t)j * K;
  const float* xr = xs + g * (8 * K);
  float acc[8] = {0.f, 0.f, 0.f, 0.f, 0.f, 0.f, 0.f, 0.f};
  for (int k = 0; k < K; k += 4) {
    float4 w4 = *(const float4*)(wr + k);
#pragma unroll
    for (int m = 0; m < 8; ++m) {
      float4 x4 = *(const float4*)(xr + m * K + k);
      acc[m] += w4.x * x4.x + w4.y * x4.y + w4.z * x4.z + w4.w * x4.w;
    }
  }
  int hd = j >> 5;
  float as = att_s[j], ad = att_d[j];
#pragma unroll
  for (int m = 0; m < 8; ++m) {
    int n = n0 + g * 8 + m;
    xh[(size_t)n * 128 + j] = acc[m];
    float vs = acc[m] * as, vd = acc[m] * ad;
#pragma unroll
    for (int off = 16; off >= 1; off >>= 1) {
      vs += __shfl_xor(vs, off);
      vd += __shfl_xor(vd, off);
    }
    if ((j & 31) == 0) {
      a_src[n * 4 + hd] = vs;
      a_dst[n * 4 + hd] = vd;
    }
  }
}

// ---------- GAT pass A: per-(node,head) segment max of leaky scores ----------
// one wave per node; lane l handles edges p = lo + (l>>2) stride 16, head = l&3.
__global__ void __launch_bounds__(256) k_gat_max(
    const float* __restrict__ a_src, const float* __restrict__ a_dst,
    const int* __restrict__ rowptr, const int* __restrict__ csr_src,
    float* __restrict__ mrow) {
  int n = blockIdx.x * 4 + (threadIdx.x >> 6);
  if (n >= kN) return;
  int lane = threadIdx.x & 63;
  int hd4 = lane & 3;
  float ad4 = a_dst[n * 4 + hd4];
  float mx = leaky(a_src[n * 4 + hd4] + ad4);  // self-loop
  int lo = rowptr[n], hi = rowptr[n + 1];
  for (int p = lo + (lane >> 2); p < hi; p += 16) {
    int s = csr_src[p];
    mx = fmaxf(mx, leaky(a_src[s * 4 + hd4] + ad4));
  }
  // reduce across the 16 lanes sharing hd4 (bits 2..5)
  mx = fmaxf(mx, __shfl_xor(mx, 4));
  mx = fmaxf(mx, __shfl_xor(mx, 8));
  mx = fmaxf(mx, __shfl_xor(mx, 16));
  mx = fmaxf(mx, __shfl_xor(mx, 32));
  if (lane < 4) mrow[n * 4 + lane] = mx;
}

// ---------- GAT pass B: exact-softmax gather + bias + LN + ReLU ----------
// one wave per dst node. phase1: lane (ed4=l>>2, hd4=l&3) computes w for one
// (edge,head). phase2: broadcast via shfl; all lanes accumulate 2 channels.
__global__ void __launch_bounds__(256) k_gat_agg(
    const float* __restrict__ xh, const float* __restrict__ a_src,
    const float* __restrict__ a_dst, const float* __restrict__ mrow,
    const int* __restrict__ rowptr, const int* __restrict__ csr_src,
    const float* __restrict__ gb, const float* __restrict__ lw,
    const float* __restrict__ lb, float* __restrict__ out) {
  int n = blockIdx.x * 4 + (threadIdx.x >> 6);
  if (n >= kN) return;
  int lane = threadIdx.x & 63;
  int hd = lane >> 4;        // own head (accumulation)
  int ch = lane * 2;         // own 2 channels
  int hd4 = lane & 3, ed4 = lane >> 2;  // phase-1 mapping
  float ad4 = a_dst[n * 4 + hd4];
  float m4 = mrow[n * 4 + hd4];

  // self-loop init (own head)
  float den, acc0, acc1;
  {
    float w_self = __expf(leaky(a_src[n * 4 + hd] + a_dst[n * 4 + hd]) - mrow[n * 4 + hd]);
    den = w_self;
    float2 xv = *(const float2*)(xh + (size_t)n * 128 + ch);
    acc0 = w_self * xv.x;
    acc1 = w_self * xv.y;
  }

  int lo = rowptr[n], hi = rowptr[n + 1];
  for (int p = lo; p < hi; ) {
    int cnt = hi - p;
    cnt = cnt < 16 ? cnt : 16;
    // phase 1: one (edge,head) per lane
    float w4 = 0.f;
    int s4 = 0;
    if (ed4 < cnt) {
      s4 = csr_src[p + ed4];
      float ev = leaky(a_src[s4 * 4 + hd4] + ad4);
      w4 = __expf(ev - m4);
    }
    // phase 2: broadcast + accumulate
#pragma unroll 4
    for (int ed = 0; ed < cnt; ++ed) {
      int s = __shfl(s4, ed * 4);
      float wv = __shfl(w4, ed * 4 + hd);
      float2 xv = *(const float2*)(xh + (size_t)s * 128 + ch);
      den += wv;
      acc0 += wv * xv.x;
      acc1 += wv * xv.y;
    }
    p += cnt;
  }

  float inv = 1.f / den;
  float v0 = acc0 * inv + gb[ch];
  float v1 = acc1 * inv + gb[ch + 1];
  // LayerNorm over 128 channels (whole wave)
  float s = v0 + v1, sq = v0 * v0 + v1 * v1;
#pragma unroll
  for (int off = 32; off >= 1; off >>= 1) {
    s += __shfl_xor(s, off);
    sq += __shfl_xor(sq, off);
  }
  float mean = s * (1.f / 128.f);
  float var = sq * (1.f / 128.f) - mean * mean;
  float rs = rsqrtf(var + LN_EPS);
  float y0 = fmaxf((v0 - mean) * rs * lw[ch] + lb[ch], 0.f);
  float y1 = fmaxf((v1 - mean) * rs * lw[ch + 1] + lb[ch + 1], 0.f);
  float2 o = {y0, y1};
  *(float2*)(out + (size_t)n * 128 + ch) = o;
}

// ---------- pooling stage 1: 64 groups x 16 chunks, partial sum/max ----------
__global__ void __launch_bounds__(128) k_pool1(
    const float* __restrict__ h, const int* __restrict__ batch,
    float* __restrict__ psum, float* __restrict__ pmax) {
  int g = blockIdx.x >> 4, chunk = blockIdx.x & (kPOOLC - 1);
  int c = threadIdx.x;  // 128 channels
  int lo, hi;
  { int a = 0, b = kN; while (a < b) { int m = (a + b) >> 1; if (batch[m] < g) a = m + 1; else b = m; } lo = a; }
  { int a = 0, b = kN; while (a < b) { int m = (a + b) >> 1; if (batch[m] < g + 1) a = m + 1; else b = m; } hi = a; }
  int len = hi - lo;
  int c0 = lo + (int)(((long long)len * chunk) / kPOOLC);
  int c1 = lo + (int)(((long long)len * (chunk + 1)) / kPOOLC);
  float s = 0.f, mx = -INFINITY;
  for (int n = c0; n < c1; ++n) {
    float v = h[(size_t)n * 128 + c];
    s += v;
    mx = fmaxf(mx, v);
  }
  psum[(size_t)blockIdx.x * 128 + c] = s;
  pmax[(size_t)blockIdx.x * 128 + c] = mx;
}

// ---------- pooling stage 2: fold 16 partials, mean divide ----------
__global__ void __launch_bounds__(128) k_pool2(
    const float* __restrict__ psum, const float* __restrict__ pmax,
    const int* __restrict__ batch, float* __restrict__ hg) {
  int g = blockIdx.x;
  int c = threadIdx.x;
  int lo, hi;
  { int a = 0, b = kN; while (a < b) { int m = (a + b) >> 1; if (batch[m] < g) a = m + 1; else b = m; } lo = a; }
  { int a = 0, b = kN; while (a < b) { int m = (a + b) >> 1; if (batch[m] < g + 1) a = m + 1; else b = m; } hi = a; }
  float s = 0.f, mx = -INFINITY;
#pragma unroll
  for (int k = 0; k < kPOOLC; ++k) {
    s += psum[(size_t)(g * kPOOLC + k) * 128 + c];
    mx = fmaxf(mx, pmax[(size_t)(g * kPOOLC + k) * 128 + c]);
  }
  int cnt = hi - lo;
  hg[g * 256 + c] = (cnt > 0) ? s / (float)cnt : 0.f;
  hg[g * 256 + 128 + c] = mx;
}

// ---------- classifier: relu(hg@W1.T+b1)@W2.T+b2 ----------
__global__ void __launch_bounds__(128) k_cls(
    const float* __restrict__ hg, const float* __restrict__ w1t,
    const float* __restrict__ b1, const float* __restrict__ w2,
    const float* __restrict__ b2, float* __restrict__ out) {
  __shared__ float row[256];
  __shared__ float o1[128];
  int g = blockIdx.x, tid = threadIdx.x;  // 128 threads
  row[tid] = hg[g * 256 + tid];
  row[tid + 128] = hg[g * 256 + 128 + tid];
  __syncthreads();
  float s = b1[tid];
  for (int k = 0; k < 256; ++k) s += row[k] * w1t[k * 128 + tid];
  o1[tid] = fmaxf(s, 0.f);
  __syncthreads();
  if (tid < 2) {
    float r = b2[tid];
    for (int j = 0; j < 128; ++j) r += o1[j] * w2[tid * 128 + j];
    out[g * 2 + tid] = r;
  }
}

extern "C" void kernel_launch(void* const* d_in, const int* in_sizes, int n_in,
                              void* d_out, int out_size, void* d_ws, size_t ws_size,
                              hipStream_t stream) {
  const float* x      = (const float*)d_in[0];
  const int*   ei     = (const int*)d_in[1];
  const float* ts     = (const float*)d_in[2];
  const int*   batch  = (const int*)d_in[3];
  const float* time_w = (const float*)d_in[4];
  const float* time_b = (const float*)d_in[5];
  const float* proj_w = (const float*)d_in[6];
  const float* proj_b = (const float*)d_in[7];
  const float* g0w    = (const float*)d_in[8];
  const float* as0    = (const float*)d_in[9];
  const float* ad0    = (const float*)d_in[10];
  const float* g0b    = (const float*)d_in[11];
  const float* ln0w   = (const float*)d_in[12];
  const float* ln0b   = (const float*)d_in[13];
  const float* g1w    = (const float*)d_in[14];
  const float* as1    = (const float*)d_in[15];
  const float* ad1    = (const float*)d_in[16];
  const float* g1b    = (const float*)d_in[17];
  const float* ln1w   = (const float*)d_in[18];
  const float* ln1b   = (const float*)d_in[19];
  const float* c1w    = (const float*)d_in[20];
  const float* c1b    = (const float*)d_in[21];
  const float* c2w    = (const float*)d_in[22];
  const float* c2b    = (const float*)d_in[23];
  float* out = (float*)d_out;

  const int* src = ei;
  const int* dst = ei + kE;

  // ---- workspace layout ----
  float* ws    = (float*)d_ws;
  float* hbuf  = ws;                                 // [N][144] (later reused as [N][128])
  float* xh    = hbuf + (size_t)kN * kDIN0;          // [N][128]
  float* a_src = xh + (size_t)kN * 128;              // [N][4]
  float* a_dst = a_src + kN * 4;                     // [N][4]
  float* mrow  = a_dst + kN * 4;                     // [N][4]
  float* c1T   = mrow + kN * 4;                      // 256x128
  float* hg    = c1T + 256 * 128;                    // [G][256]
  float* csr_ts = hg + kG * 256;                     // [E]
  int* csr_src = (int*)(csr_ts + kE);                // [E]
  int* rowptr  = csr_src + kE;                       // [N+1]
  int* deg     = rowptr + (kN + 1);                  // [N]
  int* cursor  = deg + kN;                           // [N]
  float* psum  = (float*)(cursor + kN);              // [G*16][128]
  float* pmax  = psum + kG * kPOOLC * 128;           // [G*16][128]

  // classifier weight transpose (tiny; GEMM kernels use original layouts)
  k_transpose<<<(128 * 256 + 255) / 256, 256, 0, stream>>>(c1w, c1T, 128, 256);

  // ---- CSR build (dst-sorted) ----
  hipMemsetAsync(deg, 0, kN * sizeof(int), stream);
  k_hist<<<(kE + 255) / 256, 256, 0, stream>>>(dst, deg);
  k_scan<<<1, 1024, 0, stream>>>(deg, rowptr, cursor);
  k_scatter<<<(kE + 255) / 256, 256, 0, stream>>>(src, dst, ts, cursor, csr_src, csr_ts);

  // ---- node projection + time encoding (both direct stores, no memset) ----
  k_gemm_f32<<<kN / 16, 256, 0, stream>>>(x, kFIN, kFIN, proj_w, proj_b, hbuf, kDIN0);
  k_time_gather<<<kN / 4, 256, 0, stream>>>(rowptr, csr_ts, time_w, time_b, hbuf);

  // ---- GAT layer 0 ----
  k_xh_att_f32<<<kN / 16, 256, 0, stream>>>(hbuf, kDIN0, kDIN0, g0w, as0, ad0, xh, a_src, a_dst);
  k_gat_max<<<kN / 4, 256, 0, stream>>>(a_src, a_dst, rowptr, csr_src, mrow);
  k_gat_agg<<<kN / 4, 256, 0, stream>>>(xh, a_src, a_dst, mrow, rowptr, csr_src,
                                        g0b, ln0w, ln0b, hbuf);  // hbuf now [N][128]

  // ---- GAT layer 1 ----
  k_xh_att_f32<<<kN / 16, 256, 0, stream>>>(hbuf, 128, 128, g1w, as1, ad1, xh, a_src, a_dst);
  k_gat_max<<<kN / 4, 256, 0, stream>>>(a_src, a_dst, rowptr, csr_src, mrow);
  k_gat_agg<<<kN / 4, 256, 0, stream>>>(xh, a_src, a_dst, mrow, rowptr, csr_src,
                                        g1b, ln1w, ln1b, hbuf);

  // ---- pooling + classifier ----
  k_pool1<<<kG * kPOOLC, 128, 0, stream>>>(hbuf, batch, psum, pmax);
  k_pool2<<<kG, 128, 0, stream>>>(psum, pmax, batch, hg);
  k_cls<<<kG, 128, 0, stream>>>(hg, c1T, c1b, c2w, c2b, out);
}

// Round 6
// 519.215 us; speedup vs baseline: 1.1770x; 1.1770x over previous
//
#include <hip/hip_runtime.h>
#include <math.h>

// ---- problem constants ----
static constexpr int kN     = 40000;
static constexpr int kE     = 1000000;
static constexpr int kFIN   = 128;
static constexpr int kHID   = 128;
static constexpr int kTDIM  = 16;
static constexpr int kG     = 64;
static constexpr int kDIN0  = kHID + kTDIM;   // 144
static constexpr int kPOOLC = 16;             // pooling chunks per group
static constexpr int kSCANB = (kN + 255) / 256;  // 157 scan blocks
#define LN_EPS 1e-5f
#define NEG_SLOPE 0.2f

__device__ __forceinline__ float leaky(float v) {
  return v > 0.f ? v : NEG_SLOPE * v;
}

// ---------- weight transpose: wt[k*J + j] = w[j*K + k] (classifier only) ----------
__global__ void k_transpose(const float* __restrict__ w, float* __restrict__ wt,
                            int J, int K) {
  int idx = blockIdx.x * 256 + threadIdx.x;
  if (idx >= J * K) return;
  int j = idx / K, k = idx - j * K;
  wt[k * J + j] = w[idx];
}

// ---------- CSR build ----------
__global__ void __launch_bounds__(256) k_hist(const int* __restrict__ dst, int* __restrict__ deg) {
  int e = blockIdx.x * 256 + threadIdx.x;
  if (e >= kE) return;
  atomicAdd(deg + dst[e], 1);
}

// ---- 3-phase multi-block exclusive scan of deg[0..kN) -> rowptr, cursor ----
__global__ void __launch_bounds__(256) k_scan1(const int* __restrict__ deg,
                                               int* __restrict__ partial) {
  __shared__ int sh[256];
  int t = threadIdx.x;
  int idx = blockIdx.x * 256 + t;
  int v = (idx < kN) ? deg[idx] : 0;
  sh[t] = v;
  __syncthreads();
  for (int off = 128; off >= 1; off >>= 1) {
    if (t < off) sh[t] += sh[t + off];
    __syncthreads();
  }
  if (t == 0) partial[blockIdx.x] = sh[0];
}

__global__ void __launch_bounds__(256) k_scan2(int* __restrict__ partial,
                                               int* __restrict__ rowptr) {
  __shared__ int sh[256];
  int t = threadIdx.x;
  int v = (t < kSCANB) ? partial[t] : 0;
  sh[t] = v;
  __syncthreads();
  for (int off = 1; off < 256; off <<= 1) {
    int add = (t >= off) ? sh[t - off] : 0;
    __syncthreads();
    sh[t] += add;
    __syncthreads();
  }
  if (t < kSCANB) partial[t] = sh[t] - v;        // exclusive offset per block
  if (t == 0) rowptr[kN] = sh[255];              // total
}

__global__ void __launch_bounds__(256) k_scan3(const int* __restrict__ deg,
                                               const int* __restrict__ partial,
                                               int* __restrict__ rowptr,
                                               int* __restrict__ cursor) {
  __shared__ int sh[256];
  int t = threadIdx.x;
  int idx = blockIdx.x * 256 + t;
  int v = (idx < kN) ? deg[idx] : 0;
  sh[t] = v;
  __syncthreads();
  for (int off = 1; off < 256; off <<= 1) {
    int add = (t >= off) ? sh[t - off] : 0;
    __syncthreads();
    sh[t] += add;
    __syncthreads();
  }
  if (idx < kN) {
    int val = partial[blockIdx.x] + sh[t] - v;   // exclusive scan value
    rowptr[idx] = val;
    cursor[idx] = val;
  }
}

__global__ void __launch_bounds__(256) k_scatter(
    const int* __restrict__ src, const int* __restrict__ dst,
    const float* __restrict__ ts, int* __restrict__ cursor,
    int* __restrict__ csr_src, float* __restrict__ csr_ts) {
  int e = blockIdx.x * 256 + threadIdx.x;
  if (e >= kE) return;
  int d = dst[e];
  int pos = atomicAdd(cursor + d, 1);
  csr_src[pos] = src[e];
  csr_ts[pos] = ts[e];
}

// ---------- time encoding gather: h[n,128+j] = sum_{e in(n)} cos(t_e*w[j]+b[j]) ----------
__global__ void __launch_bounds__(256) k_time_gather(
    const int* __restrict__ rowptr, const float* __restrict__ csr_ts,
    const float* __restrict__ tw, const float* __restrict__ tb,
    float* __restrict__ h) {
  int n = blockIdx.x * 4 + (threadIdx.x >> 6);
  if (n >= kN) return;
  int lane = threadIdx.x & 63;
  int j = lane & 15, grp = lane >> 4;
  float w = tw[j], b = tb[j];
  int lo = rowptr[n], hi = rowptr[n + 1];
  float s = 0.f;
  for (int p = lo + grp; p < hi; p += 4) {
    s += cosf(csr_ts[p] * w + b);
  }
  s += __shfl_xor(s, 16);
  s += __shfl_xor(s, 32);
  if (grp == 0) h[(size_t)n * kDIN0 + kHID + j] = s;
}

// ---------- GEMM: out[n,j] = bias[j] + sum_k in[n,k]*w[j,k]  (J=128) ----------
// 16 nodes/block, 8 acc/thread, float4 over k. w is ORIGINAL row-major [128][K].
__global__ void __launch_bounds__(256) k_gemm_f32(
    const float* __restrict__ in, int in_stride, int K,
    const float* __restrict__ w, const float* __restrict__ bias,
    float* __restrict__ out, int out_stride) {
  __shared__ float xs[16 * kDIN0];
  int n0 = blockIdx.x * 16;
  int tid = threadIdx.x;
  int total = 16 * K;
  for (int idx = tid * 4; idx < total; idx += 1024) {
    int nl = idx / K, k = idx - nl * K;
    *(float4*)(xs + idx) = *(const float4*)(in + (size_t)(n0 + nl) * in_stride + k);
  }
  __syncthreads();
  int j = tid & 127, g = tid >> 7;
  const float* wr = w + (size_t)j * K;
  const float* xr = xs + g * (8 * K);
  float acc[8] = {0.f, 0.f, 0.f, 0.f, 0.f, 0.f, 0.f, 0.f};
  for (int k = 0; k < K; k += 4) {
    float4 w4 = *(const float4*)(wr + k);
#pragma unroll
    for (int m = 0; m < 8; ++m) {
      float4 x4 = *(const float4*)(xr + m * K + k);
      acc[m] += w4.x * x4.x + w4.y * x4.y + w4.z * x4.z + w4.w * x4.w;
    }
  }
  float b = bias ? bias[j] : 0.f;
#pragma unroll
  for (int m = 0; m < 8; ++m)
    out[(size_t)(n0 + g * 8 + m) * out_stride + j] = acc[m] + b;
}

// ---------- xh = h @ W.T fused with att dot products (same structure) ----------
__global__ void __launch_bounds__(256) k_xh_att_f32(
    const float* __restrict__ in, int in_stride, int K,
    const float* __restrict__ w,
    const float* __restrict__ att_s, const float* __restrict__ att_d,
    float* __restrict__ xh, float* __restrict__ a_src, float* __restrict__ a_dst) {
  __shared__ float xs[16 * kDIN0];
  int n0 = blockIdx.x * 16;
  int tid = threadIdx.x;
  int total = 16 * K;
  for (int idx = tid * 4; idx < total; idx += 1024) {
    int nl = idx / K, k = idx - nl * K;
    *(float4*)(xs + idx) = *(const float4*)(in + (size_t)(n0 + nl) * in_stride + k);
  }
  __syncthreads();
  int j = tid & 127, g = tid >> 7;
  const float* wr = w + (size_t)j * K;
  const float* xr = xs + g * (8 * K);
  float acc[8] = {0.f, 0.f, 0.f, 0.f, 0.f, 0.f, 0.f, 0.f};
  for (int k = 0; k < K; k += 4) {
    float4 w4 = *(const float4*)(wr + k);
#pragma unroll
    for (int m = 0; m < 8; ++m) {
      float4 x4 = *(const float4*)(xr + m * K + k);
      acc[m] += w4.x * x4.x + w4.y * x4.y + w4.z * x4.z + w4.w * x4.w;
    }
  }
  int hd = j >> 5;
  float as = att_s[j], ad = att_d[j];
#pragma unroll
  for (int m = 0; m < 8; ++m) {
    int n = n0 + g * 8 + m;
    xh[(size_t)n * 128 + j] = acc[m];
    float vs = acc[m] * as, vd = acc[m] * ad;
#pragma unroll
    for (int off = 16; off >= 1; off >>= 1) {
      vs += __shfl_xor(vs, off);
      vd += __shfl_xor(vd, off);
    }
    if ((j & 31) == 0) {
      a_src[n * 4 + hd] = vs;
      a_dst[n * 4 + hd] = vd;
    }
  }
}

// ---------- GAT pass A: per-(node,head) segment max of leaky scores ----------
__global__ void __launch_bounds__(256) k_gat_max(
    const float* __restrict__ a_src, const float* __restrict__ a_dst,
    const int* __restrict__ rowptr, const int* __restrict__ csr_src,
    float* __restrict__ mrow) {
  int n = blockIdx.x * 4 + (threadIdx.x >> 6);
  if (n >= kN) return;
  int lane = threadIdx.x & 63;
  int hd4 = lane & 3;
  float ad4 = a_dst[n * 4 + hd4];
  float mx = leaky(a_src[n * 4 + hd4] + ad4);  // self-loop
  int lo = rowptr[n], hi = rowptr[n + 1];
  for (int p = lo + (lane >> 2); p < hi; p += 16) {
    int s = csr_src[p];
    mx = fmaxf(mx, leaky(a_src[s * 4 + hd4] + ad4));
  }
  mx = fmaxf(mx, __shfl_xor(mx, 4));
  mx = fmaxf(mx, __shfl_xor(mx, 8));
  mx = fmaxf(mx, __shfl_xor(mx, 16));
  mx = fmaxf(mx, __shfl_xor(mx, 32));
  if (lane < 4) mrow[n * 4 + lane] = mx;
}

// ---------- GAT pass B: exact-softmax gather + bias + LN + ReLU ----------
__global__ void __launch_bounds__(256) k_gat_agg(
    const float* __restrict__ xh, const float* __restrict__ a_src,
    const float* __restrict__ a_dst, const float* __restrict__ mrow,
    const int* __restrict__ rowptr, const int* __restrict__ csr_src,
    const float* __restrict__ gb, const float* __restrict__ lw,
    const float* __restrict__ lb, float* __restrict__ out) {
  int n = blockIdx.x * 4 + (threadIdx.x >> 6);
  if (n >= kN) return;
  int lane = threadIdx.x & 63;
  int hd = lane >> 4;        // own head (accumulation)
  int ch = lane * 2;         // own 2 channels
  int hd4 = lane & 3, ed4 = lane >> 2;  // phase-1 mapping
  float ad4 = a_dst[n * 4 + hd4];
  float m4 = mrow[n * 4 + hd4];

  // self-loop init (own head)
  float den, acc0, acc1;
  {
    float w_self = __expf(leaky(a_src[n * 4 + hd] + a_dst[n * 4 + hd]) - mrow[n * 4 + hd]);
    den = w_self;
    float2 xv = *(const float2*)(xh + (size_t)n * 128 + ch);
    acc0 = w_self * xv.x;
    acc1 = w_self * xv.y;
  }

  int lo = rowptr[n], hi = rowptr[n + 1];
  for (int p = lo; p < hi; ) {
    int cnt = hi - p;
    cnt = cnt < 16 ? cnt : 16;
    float w4 = 0.f;
    int s4 = 0;
    if (ed4 < cnt) {
      s4 = csr_src[p + ed4];
      float ev = leaky(a_src[s4 * 4 + hd4] + ad4);
      w4 = __expf(ev - m4);
    }
#pragma unroll 4
    for (int ed = 0; ed < cnt; ++ed) {
      int s = __shfl(s4, ed * 4);
      float wv = __shfl(w4, ed * 4 + hd);
      float2 xv = *(const float2*)(xh + (size_t)s * 128 + ch);
      den += wv;
      acc0 += wv * xv.x;
      acc1 += wv * xv.y;
    }
    p += cnt;
  }

  float inv = 1.f / den;
  float v0 = acc0 * inv + gb[ch];
  float v1 = acc1 * inv + gb[ch + 1];
  float s = v0 + v1, sq = v0 * v0 + v1 * v1;
#pragma unroll
  for (int off = 32; off >= 1; off >>= 1) {
    s += __shfl_xor(s, off);
    sq += __shfl_xor(sq, off);
  }
  float mean = s * (1.f / 128.f);
  float var = sq * (1.f / 128.f) - mean * mean;
  float rs = rsqrtf(var + LN_EPS);
  float y0 = fmaxf((v0 - mean) * rs * lw[ch] + lb[ch], 0.f);
  float y1 = fmaxf((v1 - mean) * rs * lw[ch + 1] + lb[ch + 1], 0.f);
  float2 o = {y0, y1};
  *(float2*)(out + (size_t)n * 128 + ch) = o;
}

// ---------- pooling stage 1: 64 groups x 16 chunks, partial sum/max ----------
__global__ void __launch_bounds__(128) k_pool1(
    const float* __restrict__ h, const int* __restrict__ batch,
    float* __restrict__ psum, float* __restrict__ pmax) {
  int g = blockIdx.x >> 4, chunk = blockIdx.x & (kPOOLC - 1);
  int c = threadIdx.x;  // 128 channels
  int lo, hi;
  { int a = 0, b = kN; while (a < b) { int m = (a + b) >> 1; if (batch[m] < g) a = m + 1; else b = m; } lo = a; }
  { int a = 0, b = kN; while (a < b) { int m = (a + b) >> 1; if (batch[m] < g + 1) a = m + 1; else b = m; } hi = a; }
  int len = hi - lo;
  int c0 = lo + (int)(((long long)len * chunk) / kPOOLC);
  int c1 = lo + (int)(((long long)len * (chunk + 1)) / kPOOLC);
  float s = 0.f, mx = -INFINITY;
  for (int n = c0; n < c1; ++n) {
    float v = h[(size_t)n * 128 + c];
    s += v;
    mx = fmaxf(mx, v);
  }
  psum[(size_t)blockIdx.x * 128 + c] = s;
  pmax[(size_t)blockIdx.x * 128 + c] = mx;
}

// ---------- pooling stage 2: fold 16 partials, mean divide ----------
__global__ void __launch_bounds__(128) k_pool2(
    const float* __restrict__ psum, const float* __restrict__ pmax,
    const int* __restrict__ batch, float* __restrict__ hg) {
  int g = blockIdx.x;
  int c = threadIdx.x;
  int lo, hi;
  { int a = 0, b = kN; while (a < b) { int m = (a + b) >> 1; if (batch[m] < g) a = m + 1; else b = m; } lo = a; }
  { int a = 0, b = kN; while (a < b) { int m = (a + b) >> 1; if (batch[m] < g + 1) a = m + 1; else b = m; } hi = a; }
  float s = 0.f, mx = -INFINITY;
#pragma unroll
  for (int k = 0; k < kPOOLC; ++k) {
    s += psum[(size_t)(g * kPOOLC + k) * 128 + c];
    mx = fmaxf(mx, pmax[(size_t)(g * kPOOLC + k) * 128 + c]);
  }
  int cnt = hi - lo;
  hg[g * 256 + c] = (cnt > 0) ? s / (float)cnt : 0.f;
  hg[g * 256 + 128 + c] = mx;
}

// ---------- classifier: relu(hg@W1.T+b1)@W2.T+b2 ----------
__global__ void __launch_bounds__(128) k_cls(
    const float* __restrict__ hg, const float* __restrict__ w1t,
    const float* __restrict__ b1, const float* __restrict__ w2,
    const float* __restrict__ b2, float* __restrict__ out) {
  __shared__ float row[256];
  __shared__ float o1[128];
  int g = blockIdx.x, tid = threadIdx.x;  // 128 threads
  row[tid] = hg[g * 256 + tid];
  row[tid + 128] = hg[g * 256 + 128 + tid];
  __syncthreads();
  float s = b1[tid];
  for (int k = 0; k < 256; ++k) s += row[k] * w1t[k * 128 + tid];
  o1[tid] = fmaxf(s, 0.f);
  __syncthreads();
  if (tid < 2) {
    float r = b2[tid];
    for (int j = 0; j < 128; ++j) r += o1[j] * w2[tid * 128 + j];
    out[g * 2 + tid] = r;
  }
}

extern "C" void kernel_launch(void* const* d_in, const int* in_sizes, int n_in,
                              void* d_out, int out_size, void* d_ws, size_t ws_size,
                              hipStream_t stream) {
  const float* x      = (const float*)d_in[0];
  const int*   ei     = (const int*)d_in[1];
  const float* ts     = (const float*)d_in[2];
  const int*   batch  = (const int*)d_in[3];
  const float* time_w = (const float*)d_in[4];
  const float* time_b = (const float*)d_in[5];
  const float* proj_w = (const float*)d_in[6];
  const float* proj_b = (const float*)d_in[7];
  const float* g0w    = (const float*)d_in[8];
  const float* as0    = (const float*)d_in[9];
  const float* ad0    = (const float*)d_in[10];
  const float* g0b    = (const float*)d_in[11];
  const float* ln0w   = (const float*)d_in[12];
  const float* ln0b   = (const float*)d_in[13];
  const float* g1w    = (const float*)d_in[14];
  const float* as1    = (const float*)d_in[15];
  const float* ad1    = (const float*)d_in[16];
  const float* g1b    = (const float*)d_in[17];
  const float* ln1w   = (const float*)d_in[18];
  const float* ln1b   = (const float*)d_in[19];
  const float* c1w    = (const float*)d_in[20];
  const float* c1b    = (const float*)d_in[21];
  const float* c2w    = (const float*)d_in[22];
  const float* c2b    = (const float*)d_in[23];
  float* out = (float*)d_out;

  const int* src = ei;
  const int* dst = ei + kE;

  // ---- workspace layout ----
  float* ws    = (float*)d_ws;
  float* hbuf  = ws;                                 // [N][144] (later reused as [N][128])
  float* xh    = hbuf + (size_t)kN * kDIN0;          // [N][128]
  float* a_src = xh + (size_t)kN * 128;              // [N][4]
  float* a_dst = a_src + kN * 4;                     // [N][4]
  float* mrow  = a_dst + kN * 4;                     // [N][4]
  float* c1T   = mrow + kN * 4;                      // 256x128
  float* hg    = c1T + 256 * 128;                    // [G][256]
  float* csr_ts = hg + kG * 256;                     // [E]
  int* csr_src = (int*)(csr_ts + kE);                // [E]
  int* rowptr  = csr_src + kE;                       // [N+1]
  int* deg     = rowptr + (kN + 1);                  // [N]
  int* cursor  = deg + kN;                           // [N]
  int* partial = cursor + kN;                        // [kSCANB]
  float* psum  = (float*)(partial + kSCANB);         // [G*16][128]
  float* pmax  = psum + kG * kPOOLC * 128;           // [G*16][128]

  // classifier weight transpose (tiny; GEMM kernels use original layouts)
  k_transpose<<<(128 * 256 + 255) / 256, 256, 0, stream>>>(c1w, c1T, 128, 256);

  // ---- CSR build (dst-sorted) ----
  hipMemsetAsync(deg, 0, kN * sizeof(int), stream);
  k_hist<<<(kE + 255) / 256, 256, 0, stream>>>(dst, deg);
  k_scan1<<<kSCANB, 256, 0, stream>>>(deg, partial);
  k_scan2<<<1, 256, 0, stream>>>(partial, rowptr);
  k_scan3<<<kSCANB, 256, 0, stream>>>(deg, partial, rowptr, cursor);
  k_scatter<<<(kE + 255) / 256, 256, 0, stream>>>(src, dst, ts, cursor, csr_src, csr_ts);

  // ---- node projection + time encoding (both direct stores, no memset) ----
  k_gemm_f32<<<kN / 16, 256, 0, stream>>>(x, kFIN, kFIN, proj_w, proj_b, hbuf, kDIN0);
  k_time_gather<<<kN / 4, 256, 0, stream>>>(rowptr, csr_ts, time_w, time_b, hbuf);

  // ---- GAT layer 0 ----
  k_xh_att_f32<<<kN / 16, 256, 0, stream>>>(hbuf, kDIN0, kDIN0, g0w, as0, ad0, xh, a_src, a_dst);
  k_gat_max<<<kN / 4, 256, 0, stream>>>(a_src, a_dst, rowptr, csr_src, mrow);
  k_gat_agg<<<kN / 4, 256, 0, stream>>>(xh, a_src, a_dst, mrow, rowptr, csr_src,
                                        g0b, ln0w, ln0b, hbuf);  // hbuf now [N][128]

  // ---- GAT layer 1 ----
  k_xh_att_f32<<<kN / 16, 256, 0, stream>>>(hbuf, 128, 128, g1w, as1, ad1, xh, a_src, a_dst);
  k_gat_max<<<kN / 4, 256, 0, stream>>>(a_src, a_dst, rowptr, csr_src, mrow);
  k_gat_agg<<<kN / 4, 256, 0, stream>>>(xh, a_src, a_dst, mrow, rowptr, csr_src,
                                        g1b, ln1w, ln1b, hbuf);

  // ---- pooling + classifier ----
  k_pool1<<<kG * kPOOLC, 128, 0, stream>>>(hbuf, batch, psum, pmax);
  k_pool2<<<kG, 128, 0, stream>>>(psum, pmax, batch, hg);
  k_cls<<<kG, 128, 0, stream>>>(hg, c1T, c1b, c2w, c2b, out);
}